// Round 1
// 262.262 us; speedup vs baseline: 1.0108x; 1.0108x over previous
//
#include <hip/hip_runtime.h>
#include <math.h>
#include <cstddef>

#define BB 4
#define LL 4096
#define DD 256
#define NST 8
#define RANK 16
#define HID 128
#define BL (BB*LL)          // 16384
#define BLD ((size_t)BL*DD) // 4194304
#define CH 256              // scan chunks
#define CLEN 16             // steps per chunk (CH*CLEN == LL)
#define XZS 512             // xz row stride (xin cols 0..255, z cols 256..511)

typedef __bf16 bf16x8 __attribute__((ext_vector_type(8)));
typedef float  f32x4  __attribute__((ext_vector_type(4)));

__device__ __forceinline__ float siluf(float x){ return x / (1.f + __expf(-x)); }
__device__ __forceinline__ float softplus_fast(float x){
  float r = __logf(1.f + __expf(x));
  return x > 15.f ? x : r;
}
// fp32 -> bf16 bits, round-to-nearest-even
__device__ __forceinline__ unsigned short f2bf(float x){
  union { float f; unsigned u; } v; v.f = x;
  unsigned r = v.u + 0x7fffu + ((v.u >> 16) & 1u);
  return (unsigned short)(r >> 16);
}
__device__ __forceinline__ float bf2f(unsigned short u){
  union { unsigned u32; float f; } c; c.u32 = ((unsigned)u) << 16;
  return c.f;
}

// ---------------- RMSNorm: both streams -> bf16 ----------------------------------
__global__ __launch_bounds__(64) void rms_kernel(
    const float* __restrict__ x0, const float* __restrict__ w0, unsigned short* __restrict__ o0b,
    const float* __restrict__ x1, const float* __restrict__ w1, unsigned short* __restrict__ o1b)
{
  const float* x; const float* w; unsigned short* o;
  if (blockIdx.y == 0){ x = x0; w = w0; o = o0b; } else { x = x1; w = w1; o = o1b; }
  size_t tok = blockIdx.x;
  int lane = threadIdx.x;
  float4 v = ((const float4*)(x + tok*DD))[lane];
  float s = v.x*v.x + v.y*v.y + v.z*v.z + v.w*v.w;
  #pragma unroll
  for (int m = 1; m < 64; m <<= 1) s += __shfl_xor(s, m, 64);
  float scale = 1.f / (sqrtf(s) * (1.f/16.f) + 1e-6f);
  float4 wv = ((const float4*)w)[lane];
  ushort4 r;
  r.x = f2bf(v.x*scale*wv.x); r.y = f2bf(v.y*scale*wv.y);
  r.z = f2bf(v.z*scale*wv.z); r.w = f2bf(v.w*scale*wv.w);
  ((ushort4*)(o + tok*DD))[lane] = r;
}

// ---------------- weight fp32->bf16 conversion -----------------------------------
__global__ __launch_bounds__(256) void cvt1_kernel(
    const float* __restrict__ s, unsigned short* __restrict__ d, int n)
{
  int i = blockIdx.x*256 + threadIdx.x;
  if (i < n) d[i] = f2bf(s[i]);
}
// xproj_f(8192) | xproj_bw(8192) | out_proj(65536) | fc1(32768) | fc2(32768)
__global__ __launch_bounds__(256) void cvt5_kernel(
    const float* __restrict__ s0, const float* __restrict__ s1,
    const float* __restrict__ s2, const float* __restrict__ s3,
    const float* __restrict__ s4, unsigned short* __restrict__ d)
{
  int i = blockIdx.x*256 + threadIdx.x;   // 0..147455
  if (i >= 147456) return;
  float v;
  if (i < 8192)        v = s0[i];
  else if (i < 16384)  v = s1[i - 8192];
  else if (i < 81920)  v = s2[i - 16384];
  else if (i < 114688) v = s3[i - 81920];
  else                 v = s4[i - 114688];
  d[i] = f2bf(v);
}

// ---------------- bf16 MFMA GEMM, 64x64 tile: C = A @ Bw^T (+ epilogue) ----------
// EPI: 0 = C=acc ; 1 = C=acc+Add & Cb=bf16(C) ; 2 = C=acc+Add ; 3 = Cb=bf16(acc)
// ldc = row stride of C/Cb/Add (for writing into a wider matrix)
template<int EPI>
__global__ __launch_bounds__(256) void gemm_mfma(
    const unsigned short* __restrict__ A, const unsigned short* __restrict__ Bw,
    float* __restrict__ C, const float* __restrict__ Add,
    unsigned short* __restrict__ Cb, int M, int ldc, int K)
{
  constexpr int BK = 32, PAD = 8;
  __shared__ __align__(16) unsigned short As[64][BK+PAD];
  __shared__ __align__(16) unsigned short Bs[64][BK+PAD];
  int tid  = threadIdx.x;
  int row0 = blockIdx.x * 64;
  int col0 = blockIdx.y * 64;
  int wave = tid >> 6, lane = tid & 63;
  int wm = (wave >> 1) * 32, wn = (wave & 1) * 32;
  int lm = lane & 15, kq = lane >> 4;
  int sr = tid >> 2, sc8 = (tid & 3) * 8;

  f32x4 acc[2][2];
  #pragma unroll
  for (int i = 0; i < 2; i++)
    #pragma unroll
    for (int j = 0; j < 2; j++) acc[i][j] = (f32x4){0.f,0.f,0.f,0.f};

  for (int k0 = 0; k0 < K; k0 += BK){
    *(int4*)&As[sr][sc8] = *(const int4*)&A [(size_t)(row0 + sr)*K + k0 + sc8];
    *(int4*)&Bs[sr][sc8] = *(const int4*)&Bw[(size_t)(col0 + sr)*K + k0 + sc8];
    __syncthreads();
    bf16x8 af[2], bfv[2];
    #pragma unroll
    for (int i = 0; i < 2; i++) af[i]  = *(const bf16x8*)&As[wm + i*16 + lm][kq*8];
    #pragma unroll
    for (int j = 0; j < 2; j++) bfv[j] = *(const bf16x8*)&Bs[wn + j*16 + lm][kq*8];
    #pragma unroll
    for (int i = 0; i < 2; i++)
      #pragma unroll
      for (int j = 0; j < 2; j++)
        acc[i][j] = __builtin_amdgcn_mfma_f32_16x16x32_bf16(af[i], bfv[j], acc[i][j], 0, 0, 0);
    __syncthreads();
  }

  // C/D layout: col = lane&15, row = (lane>>4)*4 + reg   [m89-verified]
  #pragma unroll
  for (int i = 0; i < 2; i++){
    int rbase = row0 + wm + i*16 + kq*4;
    #pragma unroll
    for (int j = 0; j < 2; j++){
      int col = col0 + wn + j*16 + lm;
      #pragma unroll
      for (int r = 0; r < 4; r++){
        size_t idx = (size_t)(rbase + r)*ldc + col;
        float v = acc[i][j][r];
        if constexpr (EPI == 1 || EPI == 2) v += Add[idx];
        if constexpr (EPI != 3) C[idx] = v;
        if constexpr (EPI == 1 || EPI == 3) Cb[idx] = f2bf(v);
      }
    }
  }
}

// =================== Front: conv+silu+delta + local scan w/ C-apply ==============
// Block = (chunk, b, dir). Computes xc (causal conv + silu), delta, local scan
// from h=0 *including the C contraction*, so it directly emits the local output
// y0_t = D*xc_t + sum_n C_t[n] * h_local_t[n].  Writes:
//   pack  (y0 bf16 | de bf16)  -> xde plane  (correction kernel input)
//   S     = sum of de over the chunk (fp32)  (chunk decay is exp(S*A[n]))
//   Hout  = local final state (8 floats)
// FAST path: A[n] == -(n+1)  ->  dA[n] = e1^(n+1), e1 = exp(-de).
__global__ __launch_bounds__(256) void front_kernel(
    const unsigned short* __restrict__ xz,
    const float* __restrict__ xd,
    const float* __restrict__ cwf, const float* __restrict__ cbf,
    const float* __restrict__ cwb, const float* __restrict__ cbb,
    const float* __restrict__ dtwf, const float* __restrict__ dtbf,
    const float* __restrict__ dtwb, const float* __restrict__ dtbb,
    const float* __restrict__ Alogf, const float* __restrict__ Alogb,
    const float* __restrict__ Dfp, const float* __restrict__ Dbp,
    unsigned int* __restrict__ xde,
    float* __restrict__ Sp, float* __restrict__ Hout)
{
  int chunk = blockIdx.x, b = blockIdx.y, dir = blockIdx.z;
  int s0 = chunk*CLEN;
  int d  = threadIdx.x;

  __shared__ float sdt[CLEN][16];   // 1 KB
  __shared__ float sB [CLEN][8];    // 0.5 KB
  __shared__ float sC [CLEN][8];    // 0.5 KB
  #pragma unroll
  for (int e = threadIdx.x; e < CLEN*32; e += 256){
    int lt = e >> 5, col = e & 31;
    int pos = s0 + lt;
    int row = dir ? (LL-1-pos) : pos;
    float v = xd[((size_t)b*LL + row)*64 + dir*32 + col];
    if (col < 16)      sdt[lt][col]    = v;
    else if (col < 24) sB [lt][col-16] = v;
    else               sC [lt][col-24] = v;
  }
  __syncthreads();

  float4 cw = ((const float4*)(dir ? cwb : cwf))[d];
  float cb  = (dir ? cbb : cbf)[d];
  const float* dtw = (dir ? dtwb : dtwf) + d*RANK;
  float4 w0 = ((const float4*)dtw)[0], w1 = ((const float4*)dtw)[1];
  float4 w2 = ((const float4*)dtw)[2], w3 = ((const float4*)dtw)[3];
  float dtb = (dir ? dtbb : dtbf)[d];
  float Dd  = (dir ? Dbp : Dfp)[d];

  const unsigned short* xp = xz + (size_t)b*LL*XZS + d;
  #define LDX(pos) ((pos) >= 0 ? bf2f(xp[(size_t)(dir ? (LL-1-(pos)) : (pos))*XZS]) : 0.f)

  // ---- phase 1: conv + silu + delta, packed into regs ----
  float xv[CLEN+3];
  xv[0] = LDX(s0-3); xv[1] = LDX(s0-2); xv[2] = LDX(s0-1);
  #pragma unroll
  for (int i = 0; i < CLEN; i++) xv[3+i] = LDX(s0+i);
  #undef LDX

  unsigned packX[CLEN];
  #pragma unroll
  for (int i = 0; i < CLEN; i++){
    float xc = cb;
    xc = fmaf(cw.x, xv[i],   xc); xc = fmaf(cw.y, xv[i+1], xc);
    xc = fmaf(cw.z, xv[i+2], xc); xc = fmaf(cw.w, xv[i+3], xc);
    xc = siluf(xc);
    const float* dt = &sdt[i][0];
    float de = dtb;
    de = fmaf(dt[0],w0.x, fmaf(dt[1],w0.y, fmaf(dt[2],w0.z, fmaf(dt[3],w0.w, de))));
    de = fmaf(dt[4],w1.x, fmaf(dt[5],w1.y, fmaf(dt[6],w1.z, fmaf(dt[7],w1.w, de))));
    de = fmaf(dt[8],w2.x, fmaf(dt[9],w2.y, fmaf(dt[10],w2.z, fmaf(dt[11],w2.w, de))));
    de = fmaf(dt[12],w3.x, fmaf(dt[13],w3.y, fmaf(dt[14],w3.z, fmaf(dt[15],w3.w, de))));
    de = softplus_fast(de);
    packX[i] = (unsigned)f2bf(xc) | ((unsigned)f2bf(de) << 16);
  }

  // ---- phase 2: local scan (h from 0) with C-apply; write pack (y0,de) ----
  const float* Alog = dir ? Alogb : Alogf;
  float A[NST];
  bool fast = true;
  #pragma unroll
  for (int n = 0; n < NST; n++){
    A[n] = -__expf(Alog[d*NST + n]);
    fast = fast && (fabsf(A[n] + (float)(n+1)) < 1e-3f);
  }
  float h[NST];
  #pragma unroll
  for (int n = 0; n < NST; n++) h[n] = 0.f;
  float S = 0.f;

  unsigned int* xout = xde + ((size_t)(dir*BB + b)*LL + s0)*DD + d;

  if (fast){
    #pragma unroll
    for (int t = 0; t < CLEN; t++){
      unsigned pk = packX[t];
      float xc = bf2f((unsigned short)(pk & 0xffffu));
      float de = bf2f((unsigned short)(pk >> 16));
      S += de;
      float dux = de * xc;
      const float* Bv = &sB[t][0];
      const float* Cv = &sC[t][0];
      float e1 = __expf(-de);
      float dA = e1;
      float acc = xc * Dd;
      h[0] = fmaf(dA, h[0], dux*Bv[0]); acc = fmaf(h[0], Cv[0], acc); dA *= e1;
      h[1] = fmaf(dA, h[1], dux*Bv[1]); acc = fmaf(h[1], Cv[1], acc); dA *= e1;
      h[2] = fmaf(dA, h[2], dux*Bv[2]); acc = fmaf(h[2], Cv[2], acc); dA *= e1;
      h[3] = fmaf(dA, h[3], dux*Bv[3]); acc = fmaf(h[3], Cv[3], acc); dA *= e1;
      h[4] = fmaf(dA, h[4], dux*Bv[4]); acc = fmaf(h[4], Cv[4], acc); dA *= e1;
      h[5] = fmaf(dA, h[5], dux*Bv[5]); acc = fmaf(h[5], Cv[5], acc); dA *= e1;
      h[6] = fmaf(dA, h[6], dux*Bv[6]); acc = fmaf(h[6], Cv[6], acc); dA *= e1;
      h[7] = fmaf(dA, h[7], dux*Bv[7]); acc = fmaf(h[7], Cv[7], acc);
      xout[(size_t)t*DD] = (pk & 0xffff0000u) | (unsigned)f2bf(acc);
    }
  } else {
    #pragma unroll
    for (int t = 0; t < CLEN; t++){
      unsigned pk = packX[t];
      float xc = bf2f((unsigned short)(pk & 0xffffu));
      float de = bf2f((unsigned short)(pk >> 16));
      S += de;
      float dux = de * xc;
      const float* Bv = &sB[t][0];
      const float* Cv = &sC[t][0];
      float acc = xc * Dd;
      #pragma unroll
      for (int n = 0; n < NST; n++){
        h[n] = fmaf(__expf(de*A[n]), h[n], dux*Bv[n]);
        acc = fmaf(h[n], Cv[n], acc);
      }
      xout[(size_t)t*DD] = (pk & 0xffff0000u) | (unsigned)f2bf(acc);
    }
  }

  size_t ob = ((((size_t)dir*CH + chunk)*BB + b)*DD + d)*NST;
  float4 h0v, h1v;
  h0v.x=h[0]; h0v.y=h[1]; h0v.z=h[2]; h0v.w=h[3];
  h1v.x=h[4]; h1v.y=h[5]; h1v.z=h[6]; h1v.w=h[7];
  *(float4*)&Hout[ob]   = h0v; *(float4*)&Hout[ob+4] = h1v;
  Sp[((size_t)(dir*CH + chunk)*BB + b)*DD + d] = S;
}

// Phase 2: chunk-carry scan, 2-level. Block = (dir,b,d) -> 2048 one-wave blocks
// (8 waves/CU vs the old 1). Lane = (seg, n): 8 segments x 32 chunks, 8 states.
// Chunk decay p_c = exp(S_c * A[n]); segment decay = exp(sum(S)*A[n]) -- sums,
// so no product chains. Pair-scan (P,H) across segments via 3 shfl_up steps,
// then seeded re-apply from registers (no reloads). Hin overwrites Hout in
// place (each (c,d,n) slot owned by exactly one lane; read-before-write).
__global__ __launch_bounds__(64) void scan_p2(
    const float* __restrict__ Sp, float* H,
    const float* __restrict__ Alogf, const float* __restrict__ Alogb)
{
  const int SEGC = CH/8;    // 32 chunks per segment
  int blk = blockIdx.x;
  int d   = blk & (DD-1);
  int b   = (blk >> 8) & (BB-1);
  int dir = blk >> 10;
  int t   = threadIdx.x;
  int seg = t >> 3, n = t & 7;
  float A = -__expf((dir ? Alogb : Alogf)[d*NST + n]);

  const size_t sstr = (size_t)BB*DD;          // per-chunk stride in Sp
  const size_t hstr = (size_t)BB*DD*NST;      // per-chunk stride in H
  size_t sb = (size_t)dir*CH*sstr + (size_t)b*DD + d;
  size_t hb = (size_t)dir*CH*hstr + ((size_t)b*DD + d)*NST + n;
  int c0 = seg*SEGC;

  float pv[SEGC], hv[SEGC];
  #pragma unroll
  for (int k = 0; k < SEGC; k++){
    pv[k] = Sp[sb + (size_t)(c0+k)*sstr];
    hv[k] = H [hb + (size_t)(c0+k)*hstr];
  }
  // segment aggregate
  float h = 0.f, Ss = 0.f;
  #pragma unroll
  for (int k = 0; k < SEGC; k++){
    Ss += pv[k];
    pv[k] = __expf(pv[k]*A);
    h = fmaf(pv[k], h, hv[k]);
  }
  // inclusive pair-scan over segments: (Pl,Hl)o(Pr,Hr) = (Pl*Pr, Pr*Hl+Hr)
  float pi = __expf(Ss*A), hi = h;
  #pragma unroll
  for (int off = 8; off < 64; off <<= 1){
    float hprev = __shfl_up(hi, off, 64);
    float pprev = __shfl_up(pi, off, 64);
    if (t >= off){ hi = fmaf(pi, hprev, hi); pi *= pprev; }
  }
  float hin = __shfl_up(hi, 8, 64);
  h = (seg == 0) ? 0.f : hin;
  // seeded re-apply: write carry-in per chunk (over Hout), fold forward
  #pragma unroll
  for (int k = 0; k < SEGC; k++){
    size_t idx = hb + (size_t)(c0+k)*hstr;
    H[idx] = h;
    h = fmaf(pv[k], h, hv[k]);
  }
}

// Phase 3 replacement: correction. y_t = y0_t + sum_n C_t[n]*exp(S_t*A[n])*h_in[n]
// S_t recomputed by a serial ADD chain over the packed de (bit-identical to the
// front's accumulation). No state-vector recurrence -> fully pipelineable.
__global__ __launch_bounds__(256) void scan_corr(
    const unsigned int* __restrict__ xde,
    const float* __restrict__ xd,
    const float* __restrict__ Alogf, const float* __restrict__ Alogb,
    const float* __restrict__ Hin,
    unsigned short* __restrict__ yf, unsigned short* __restrict__ yb)
{
  int chunk = blockIdx.x, b = blockIdx.y, dir = blockIdx.z;
  int d = threadIdx.x;
  int base = chunk*CLEN;

  __shared__ float sC[CLEN][8];    // 0.5 KB
  if (threadIdx.x < CLEN*8){
    int lt = threadIdx.x >> 3, col = threadIdx.x & 7;
    int pos = base + lt;
    int row = dir ? (LL-1-pos) : pos;
    sC[lt][col] = xd[((size_t)b*LL + row)*64 + dir*32 + 24 + col];
  }
  __syncthreads();

  const float* Alog = dir ? Alogb : Alogf;
  float A[NST];
  bool fast = true;
  #pragma unroll
  for (int n = 0; n < NST; n++){
    A[n] = -__expf(Alog[d*NST + n]);
    fast = fast && (fabsf(A[n] + (float)(n+1)) < 1e-3f);
  }
  float hn[NST];
  {
    size_t ib = ((((size_t)dir*CH + chunk)*BB + b)*DD + d)*NST;
    float4 a0 = *(const float4*)&Hin[ib];
    float4 a1 = *(const float4*)&Hin[ib+4];
    hn[0]=a0.x; hn[1]=a0.y; hn[2]=a0.z; hn[3]=a0.w;
    hn[4]=a1.x; hn[5]=a1.y; hn[6]=a1.z; hn[7]=a1.w;
  }

  const unsigned int* xdep = xde + ((size_t)(dir*BB + b)*LL + base)*DD + d;
  unsigned short* yp = (dir ? yb : yf) + ((size_t)b*LL + base)*DD + d;

  unsigned int pk[CLEN];
  #pragma unroll
  for (int t = 0; t < CLEN; t++) pk[t] = xdep[(size_t)t*DD];

  float S = 0.f;
  if (fast){
    #pragma unroll
    for (int t = 0; t < CLEN; t++){
      float y0 = bf2f((unsigned short)(pk[t] & 0xffffu));
      float de = bf2f((unsigned short)(pk[t] >> 16));
      S += de;
      float E = __expf(-S);
      float q = E;
      float corr = q * (hn[0]*sC[t][0]);
      q *= E; corr = fmaf(q, hn[1]*sC[t][1], corr);
      q *= E; corr = fmaf(q, hn[2]*sC[t][2], corr);
      q *= E; corr = fmaf(q, hn[3]*sC[t][3], corr);
      q *= E; corr = fmaf(q, hn[4]*sC[t][4], corr);
      q *= E; corr = fmaf(q, hn[5]*sC[t][5], corr);
      q *= E; corr = fmaf(q, hn[6]*sC[t][6], corr);
      q *= E; corr = fmaf(q, hn[7]*sC[t][7], corr);
      yp[(size_t)t*DD] = f2bf(y0 + corr);
    }
  } else {
    #pragma unroll
    for (int t = 0; t < CLEN; t++){
      float y0 = bf2f((unsigned short)(pk[t] & 0xffffu));
      float de = bf2f((unsigned short)(pk[t] >> 16));
      S += de;
      float corr = 0.f;
      #pragma unroll
      for (int n = 0; n < NST; n++)
        corr = fmaf(__expf(S*A[n]), hn[n]*sC[t][n], corr);
      yp[(size_t)t*DD] = f2bf(y0 + corr);
    }
  }
}

// ---------------- Combine: y=(yf+flip(yb))/2 -> rmsnorm -> *silu(z) -> bf16 ------
__global__ __launch_bounds__(64) void combine_kernel(
    const unsigned short* __restrict__ yf, const unsigned short* __restrict__ yb,
    const unsigned short* __restrict__ xz, const float* __restrict__ wn,
    unsigned short* __restrict__ outb)
{
  size_t tok = blockIdx.x;
  int b = (int)(tok / LL), t = (int)(tok % LL);
  int lane = threadIdx.x;
  ushort4 au = ((const ushort4*)(yf + tok*DD))[lane];
  ushort4 cu = ((const ushort4*)(yb + ((size_t)b*LL + (LL-1-t))*DD))[lane];
  float4 v;
  v.x=(bf2f(au.x)+bf2f(cu.x))*0.5f; v.y=(bf2f(au.y)+bf2f(cu.y))*0.5f;
  v.z=(bf2f(au.z)+bf2f(cu.z))*0.5f; v.w=(bf2f(au.w)+bf2f(cu.w))*0.5f;
  float s = v.x*v.x + v.y*v.y + v.z*v.z + v.w*v.w;
  #pragma unroll
  for (int m = 1; m < 64; m <<= 1) s += __shfl_xor(s, m, 64);
  float scale = 1.f / (sqrtf(s)*(1.f/16.f) + 1e-6f);
  float4 wv = ((const float4*)wn)[lane];
  ushort4 zv = *(const ushort4*)&xz[tok*XZS + 256 + lane*4];
  ushort4 r;
  r.x = f2bf(v.x*scale*wv.x*siluf(bf2f(zv.x)));
  r.y = f2bf(v.y*scale*wv.y*siluf(bf2f(zv.y)));
  r.z = f2bf(v.z*scale*wv.z*siluf(bf2f(zv.z)));
  r.w = f2bf(v.w*scale*wv.w*siluf(bf2f(zv.w)));
  ((ushort4*)(outb + tok*DD))[lane] = r;
}

// ---------------- FF depthwise conv k=3 pad(1,1) + SiLU -> bf16 ------------------
__global__ __launch_bounds__(256) void dwconv3_kernel(
    const float* __restrict__ m, const float* __restrict__ w,
    const float* __restrict__ bi, unsigned short* __restrict__ o)
{
  size_t gid = (size_t)blockIdx.x*256 + threadIdx.x;  // over BL*HID
  int c = (int)(gid % HID);
  int tok = (int)(gid / HID);
  int b = tok / LL, t = tok % LL;
  float acc = bi[c];
  #pragma unroll
  for (int k = 0; k < 3; k++){
    int tt = t - 1 + k;
    if (tt >= 0 && tt < LL)
      acc = fmaf(w[c*3 + k], m[((size_t)b*LL + tt)*HID + c], acc);
  }
  o[gid] = f2bf(siluf(acc));
}

extern "C" void kernel_launch(void* const* d_in, const int* in_sizes, int n_in,
                              void* d_out, int out_size, void* d_ws, size_t ws_size,
                              hipStream_t stream)
{
  const float* x0        = (const float*)d_in[0];
  const float* x1        = (const float*)d_in[1];
  const float* w_norm0   = (const float*)d_in[2];
  const float* w_norm1   = (const float*)d_in[3];
  const float* in_proj_w = (const float*)d_in[4];
  const float* conv_w_f  = (const float*)d_in[5];
  const float* conv_b_f  = (const float*)d_in[6];
  const float* xproj_w_f = (const float*)d_in[7];
  const float* dtproj_w_f= (const float*)d_in[8];
  const float* dtproj_b_f= (const float*)d_in[9];
  const float* A_log_f   = (const float*)d_in[10];
  const float* D_f       = (const float*)d_in[11];
  const float* conv_w_bw = (const float*)d_in[12];
  const float* conv_b_bw = (const float*)d_in[13];
  const float* xproj_w_bw= (const float*)d_in[14];
  const float* dtproj_w_bw=(const float*)d_in[15];
  const float* dtproj_b_bw=(const float*)d_in[16];
  const float* A_log_bw  = (const float*)d_in[17];
  const float* D_bw      = (const float*)d_in[18];
  const float* norm_y_w  = (const float*)d_in[19];
  const float* out_proj_w= (const float*)d_in[20];
  const float* fc1_w     = (const float*)d_in[21];
  const float* dw_w      = (const float*)d_in[22];
  const float* dw_b      = (const float*)d_in[23];
  const float* fc2_w     = (const float*)d_in[24];
  float* out = (float*)d_out;
  float* ws  = (float*)d_ws;

  // region map (floats, BLD each), lifetime-reused
  float* r0 = ws + 0*BLD;   // h0b (bf16) -> yfb (bf16)
  float* r1 = ws + 1*BLD;   // h1b (bf16) -> ybb (bf16)
  float* r2 = ws + 2*BLD;   // xz_b (bf16, BL x 512 = full region)
  float* r3 = ws + 3*BLD;   // xd (fp32 BLx64, 4MB) ; ycomb_b (bf16, after corr)
  float* r4 = ws + 4*BLD;   // xde pack (y0,de) (uint32, spans r4+r5) -> m1 (fp32)
  float* r5 = ws + 5*BLD;   //                                       -> m2b (bf16)
  float* r6 = ws + 6*BLD;   // wbuf1 (bf16 in_proj) -> Hout (= Hin, in-place p2)
  float* r7 = ws + 7*BLD;   // wbuf2 (bf16 weights) + xb (bf16) + S-plane (tail)

  unsigned short* h0b   = (unsigned short*)r0;
  unsigned short* h1b   = (unsigned short*)r1;
  unsigned short* xz_b  = (unsigned short*)r2;   // BL x XZS
  float*          xd    = r3;                    // BL x 64 fp32
  unsigned int*   xde   = (unsigned int*)r4;     // 2*BLD dwords = r4+r5
  unsigned short* wbuf1 = (unsigned short*)r6;   // 131072 (512x256)
  unsigned short* yfb   = (unsigned short*)r0;
  unsigned short* ybb   = (unsigned short*)r1;
  float* Hout = r6;                              // 2*CH*BB*DD*NST = BLD floats
  float* Hin  = Hout;                            // p2 rewrites in place
  const size_t SPLANE = (size_t)2*CH*BB*DD;      // 524288 floats (2 MB)
  float* Sp   = r7 + (BLD - SPLANE);             // tail of r7 (disjoint from wbuf2/xb)
  unsigned short* ycomb_b = (unsigned short*)r3; // overwrites dead xd after corr
  unsigned short* wbuf2   = (unsigned short*)r7;
  unsigned short* wb_xp   = wbuf2;               // 16384  (64x256)
  unsigned short* wb_out  = wbuf2 + 16384;       // 65536
  unsigned short* wb_fc1  = wbuf2 + 81920;       // 32768
  unsigned short* wb_fc2  = wbuf2 + 114688;      // 32768
  unsigned short* xb      = wbuf2 + 147456;      // BLD bf16
  float*          m1      = r4;
  unsigned short* m2b     = (unsigned short*)r5;

  // 0. weight conversions
  cvt1_kernel<<<dim3(512), 256, 0, stream>>>(in_proj_w, wbuf1, 131072);
  cvt5_kernel<<<dim3(576), 256, 0, stream>>>(
      xproj_w_f, xproj_w_bw, out_proj_w, fc1_w, fc2_w, wbuf2);

  // 1. RMSNorm x0 -> h0b, x1 -> h1b (both bf16)
  rms_kernel<<<dim3(BL,2), 64, 0, stream>>>(x0, w_norm0, h0b, x1, w_norm1, h1b);

  // 2. xz = h0 @ in_proj.T -> xz_b (bf16, one N=512 dispatch)
  gemm_mfma<3><<<dim3(BL/64, 8), 256, 0, stream>>>(
      h0b, wbuf1, nullptr, nullptr, xz_b, BL, XZS, 256);

  // 3. merged xproj: xd[t][0..31]=fwd dt/B/C, [32..63]=bwd (natural t order)
  gemm_mfma<0><<<dim3(BL/64, 1), 256, 0, stream>>>(
      h1b, wb_xp, xd, nullptr, nullptr, BL, 64, 256);

  // 4. front: conv+silu+delta + local scan w/ C-apply -> pack(y0,de), S, Hout
  front_kernel<<<dim3(CH, BB, 2), 256, 0, stream>>>(
      xz_b, xd, conv_w_f, conv_b_f, conv_w_bw, conv_b_bw,
      dtproj_w_f, dtproj_b_f, dtproj_w_bw, dtproj_b_bw,
      A_log_f, A_log_bw, D_f, D_bw, xde, Sp, Hout);

  // 5. chunk-carry scan (2-level, in-place Hout->Hin)
  scan_p2<<<dim3(2*BB*DD), 64, 0, stream>>>(Sp, Hout, A_log_f, A_log_bw);

  // 6. correction: y = y0 + C . exp(S*A) . h_in  -> yf/yb (bf16)
  scan_corr<<<dim3(CH, BB, 2), 256, 0, stream>>>(
      xde, xd, A_log_f, A_log_bw, Hin, yfb, ybb);

  // 7. combine + rmsnorm + gate -> ycomb_b (r3; xd dead)
  combine_kernel<<<dim3(BL), 64, 0, stream>>>(yfb, ybb, xz_b, norm_y_w, ycomb_b);

  // 8. x = y @ out_proj.T + residual(x0) -> d_out (fp32) + xb (bf16)
  gemm_mfma<1><<<dim3(BL/64, 4), 256, 0, stream>>>(
      ycomb_b, wb_out, out, x0, xb, BL, 256, 256);

  // 9. m1 = x @ fc1.T (fp32; overwrites dead xde)
  gemm_mfma<0><<<dim3(BL/64, 2), 256, 0, stream>>>(
      xb, wb_fc1, m1, nullptr, nullptr, BL, 128, 256);

  // 10. m2 = silu(dwconv3(m1)) -> bf16
  dwconv3_kernel<<<dim3((BL*HID)/256), 256, 0, stream>>>(m1, dw_w, dw_b, m2b);

  // 11. out = x + m2 @ fc2.T
  gemm_mfma<2><<<dim3(BL/64, 4), 256, 0, stream>>>(
      m2b, wb_fc2, out, out, nullptr, BL, 256, 128);
}